// Round 4
// baseline (518.204 us; speedup 1.0000x reference)
//
#include <hip/hip_runtime.h>

#define B   32
#define TK  2048
#define N   1024
#define NF4 256   // N/4

// out layout (floats): c_t [B*N] at 0, attn_dist [B*TK] at 32768, coverage_out [B*TK] at 98304
#define OUT_CT   0
#define OUT_ATTN (B * N)
#define OUT_COV  (B * N + B * TK)

#define NS   32            // n-slabs for fused ct kernel
#define SF4  (NF4 / NS)    // 8 float4 (32 floats) per slab

typedef float v4f __attribute__((ext_vector_type(4)));

__device__ __forceinline__ float hw_exp2(float x) {
    return __builtin_amdgcn_exp2f(x);   // v_exp_f32: D = 2^S0
}

__device__ __forceinline__ float fast_tanh(float x) {
    // tanh(x) = 1 - 2/(exp2(2*log2e*x)+1); stable for all x (saturates to +-1)
    float t = hw_exp2(x * 2.8853900817779268f);
    return 1.0f - 2.0f * __builtin_amdgcn_rcpf(t + 1.0f);
}

__device__ __forceinline__ float wave_reduce_sum(float v) {
#pragma unroll
    for (int off = 32; off > 0; off >>= 1) v += __shfl_xor(v, off, 64);
    return v;
}

// non-temporal float4 load: EF/EO are stream-once, keep them out of L2/L3.
__device__ __forceinline__ float4 ldnt(const float4* p) {
    v4f v = __builtin_nontemporal_load((const v4f*)p);
    return make_float4(v.x, v.y, v.z, v.w);
}

// Kernel 1: dec_fea[b][n] = sum_k s_t_hat[b][k] * W_dec[n][k] + b_dec[n]
// one wave per (n, group of 4 b). 8192 waves -> 2048 blocks of 256.
__global__ __launch_bounds__(256) void decfea_kernel(
    const float4* __restrict__ S,      // s_t_hat as float4 [B*NF4]
    const float4* __restrict__ W,      // W_dec as float4 [N*NF4]
    const float*  __restrict__ bias,   // b_dec [N]
    float*        __restrict__ dec)    // [B*N]
{
    int w    = blockIdx.x * 4 + (threadIdx.x >> 6);  // 0..8191
    int lane = threadIdx.x & 63;
    int n    = w >> 3;
    int b0   = (w & 7) * 4;

    float4 wr[4];
#pragma unroll
    for (int j = 0; j < 4; ++j) wr[j] = W[n * NF4 + j * 64 + lane];

#pragma unroll
    for (int i = 0; i < 4; ++i) {
        int b = b0 + i;
        float acc = 0.0f;
#pragma unroll
        for (int j = 0; j < 4; ++j) {
            float4 s4 = S[b * NF4 + j * 64 + lane];
            acc += s4.x * wr[j].x + s4.y * wr[j].y + s4.z * wr[j].z + s4.w * wr[j].w;
        }
        acc = wave_reduce_sum(acc);
        if (lane == 0) dec[b * N + n] = acc + bias[n];
    }
}

// Kernel 2: scores[r] = sum_n tanh(EF[r][n] + dec[b][n] + cov[r]*W_c[n]) * v_w[n]
// one wave per FOUR consecutive rows (same b) -> DEC/WC/VW loads amortize 4x.
// 16384 waves -> 4096 blocks of 256.
__global__ __launch_bounds__(256) void scores_kernel(
    const float4* __restrict__ EF,    // encoder_feature [B*TK*NF4]
    const float4* __restrict__ DEC,   // dec_fea [B*NF4]
    const float4* __restrict__ WC,    // W_c [NF4]
    const float4* __restrict__ VW,    // v_w [NF4]
    const float*  __restrict__ cov,   // coverage [B*TK]
    float*        __restrict__ scores)
{
    int w    = blockIdx.x * 4 + (threadIdx.x >> 6);  // 0..16383
    int lane = threadIdx.x & 63;
    int r0   = w * 4;                 // rows r0..r0+3 (same b: TK % 4 == 0)
    int b    = r0 >> 11;              // TK = 2048
    float c0 = cov[r0], c1 = cov[r0 + 1], c2 = cov[r0 + 2], c3 = cov[r0 + 3];

    const float4* ef = EF + (size_t)r0 * NF4;
    const float4* de = DEC + b * NF4;

    float p0 = 0.0f, p1 = 0.0f, p2 = 0.0f, p3 = 0.0f;
#pragma unroll
    for (int j = 0; j < 4; ++j) {
        int f = j * 64 + lane;
        float4 e0 = ldnt(ef + f);
        float4 e1 = ldnt(ef + NF4 + f);
        float4 e2 = ldnt(ef + 2 * NF4 + f);
        float4 e3 = ldnt(ef + 3 * NF4 + f);
        float4 d  = de[f];
        float4 wc = WC[f];
        float4 vw = VW[f];
        p0 += fast_tanh(e0.x + d.x + c0 * wc.x) * vw.x;
        p0 += fast_tanh(e0.y + d.y + c0 * wc.y) * vw.y;
        p0 += fast_tanh(e0.z + d.z + c0 * wc.z) * vw.z;
        p0 += fast_tanh(e0.w + d.w + c0 * wc.w) * vw.w;
        p1 += fast_tanh(e1.x + d.x + c1 * wc.x) * vw.x;
        p1 += fast_tanh(e1.y + d.y + c1 * wc.y) * vw.y;
        p1 += fast_tanh(e1.z + d.z + c1 * wc.z) * vw.z;
        p1 += fast_tanh(e1.w + d.w + c1 * wc.w) * vw.w;
        p2 += fast_tanh(e2.x + d.x + c2 * wc.x) * vw.x;
        p2 += fast_tanh(e2.y + d.y + c2 * wc.y) * vw.y;
        p2 += fast_tanh(e2.z + d.z + c2 * wc.z) * vw.z;
        p2 += fast_tanh(e2.w + d.w + c2 * wc.w) * vw.w;
        p3 += fast_tanh(e3.x + d.x + c3 * wc.x) * vw.x;
        p3 += fast_tanh(e3.y + d.y + c3 * wc.y) * vw.y;
        p3 += fast_tanh(e3.z + d.z + c3 * wc.z) * vw.z;
        p3 += fast_tanh(e3.w + d.w + c3 * wc.w) * vw.w;
    }
    p0 = wave_reduce_sum(p0);
    p1 = wave_reduce_sum(p1);
    p2 = wave_reduce_sum(p2);
    p3 = wave_reduce_sum(p3);
    if (lane == 0) {
        *(float4*)(scores + r0) = make_float4(p0, p1, p2, p3);
    }
}

// Kernel 3 (fused): per-block softmax recompute (redundant across the 32 n-slabs
// of a b, but scores/mask/stmt are L2-resident) + c_t accumulation over all t
// for this block's n-slab + direct epilogue writes. Slab-0 blocks also write
// attn_dist and coverage_out. grid (NS, B) = 1024 blocks of 256.
__global__ __launch_bounds__(256) void ct_fused_kernel(
    const float4* __restrict__ EO,       // encoder_outputs [B*TK*NF4]
    const float*  __restrict__ scores,   // [B*TK]
    const float*  __restrict__ mask,
    const float*  __restrict__ stmt,
    const float*  __restrict__ coverage,
    float*        __restrict__ out)
{
    int s   = blockIdx.x;   // n-slab 0..NS-1
    int b   = blockIdx.y;   // 0..B-1
    int tid = threadIdx.x;

    __shared__ __align__(16) float attn_s[TK];  // 8 KB; reused for partial reduce
    __shared__ float red[256];

    // --- Phase A: softmax + mask/renorm/stmt into LDS ---
    float sc[8];
    float m = -1e30f;
#pragma unroll
    for (int k = 0; k < 8; ++k) {
        sc[k] = scores[b * TK + k * 256 + tid];
        m = fmaxf(m, sc[k]);
    }
    red[tid] = m;
    __syncthreads();
    for (int step = 128; step > 0; step >>= 1) {
        if (tid < step) red[tid] = fmaxf(red[tid], red[tid + step]);
        __syncthreads();
    }
    float M = red[0];
    __syncthreads();

    float e[8];
    float loc = 0.0f;
#pragma unroll
    for (int k = 0; k < 8; ++k) {
        int t = k * 256 + tid;
        e[k] = hw_exp2((sc[k] - M) * 1.4426950408889634f) * mask[b * TK + t];
        loc += e[k];
    }
    red[tid] = loc;
    __syncthreads();
    for (int step = 128; step > 0; step >>= 1) {
        if (tid < step) red[tid] += red[tid + step];
        __syncthreads();
    }
    float inv = 1.0f / red[0];

#pragma unroll
    for (int k = 0; k < 8; ++k) {
        int t = k * 256 + tid;
        int r = b * TK + t;
        float a = e[k] * inv + stmt[r] * mask[r];
        attn_s[t] = a;
        if (s == 0) {                    // uniform branch: one slab owns the writes
            out[OUT_ATTN + r] = a;
            out[OUT_COV + r]  = coverage[r] + a;
        }
    }
    __syncthreads();

    // --- Phase B: acc over all t for this slab's 8 float4 of n ---
    // t = i*32 + c: lane groups have distinct c mod 32 -> conflict-free LDS reads.
    int f = tid & 7;        // float4 within slab
    int c = tid >> 3;       // 0..31 t-offset
    float4 acc = {0.0f, 0.0f, 0.0f, 0.0f};
    const float4* eo = EO + ((size_t)b * TK + c) * NF4 + s * SF4 + f;
#pragma unroll 8
    for (int i = 0; i < 64; ++i) {
        float wgt = attn_s[i * 32 + c];
        float4 v  = ldnt(eo + (size_t)i * 32 * NF4);
        acc.x += wgt * v.x;
        acc.y += wgt * v.y;
        acc.z += wgt * v.z;
        acc.w += wgt * v.w;
    }
    __syncthreads();        // all attn_s reads done; reuse LDS for partials

    // --- Phase C: reduce 32 t-partials per float4, write c_t ---
    float4* part = (float4*)attn_s;     // 256 float4 = 4 KB
    part[tid] = acc;
    __syncthreads();
    if (tid < SF4) {
        float4 sum = {0.0f, 0.0f, 0.0f, 0.0f};
#pragma unroll
        for (int cc = 0; cc < 32; ++cc) {
            float4 v = part[cc * SF4 + tid];
            sum.x += v.x; sum.y += v.y; sum.z += v.z; sum.w += v.w;
        }
        ((float4*)(out + OUT_CT))[b * NF4 + s * SF4 + tid] = sum;
    }
}

extern "C" void kernel_launch(void* const* d_in, const int* in_sizes, int n_in,
                              void* d_out, int out_size, void* d_ws, size_t ws_size,
                              hipStream_t stream) {
    const float* s_t_hat = (const float*)d_in[0];
    const float* EO      = (const float*)d_in[1];
    const float* EF      = (const float*)d_in[2];
    const float* stmt    = (const float*)d_in[3];
    const float* mask    = (const float*)d_in[4];
    const float* cov     = (const float*)d_in[5];
    const float* Wdec    = (const float*)d_in[6];
    const float* bdec    = (const float*)d_in[7];
    const float* vw      = (const float*)d_in[8];
    const float* wc      = (const float*)d_in[9];

    float* out = (float*)d_out;
    float* ws  = (float*)d_ws;
    float* dec    = ws;           // 32768 floats
    float* scores = ws + B * N;   // 65536 floats

    decfea_kernel<<<2048, 256, 0, stream>>>(
        (const float4*)s_t_hat, (const float4*)Wdec, bdec, dec);

    scores_kernel<<<4096, 256, 0, stream>>>(
        (const float4*)EF, (const float4*)dec, (const float4*)wc,
        (const float4*)vw, cov, scores);

    ct_fused_kernel<<<dim3(NS, B), 256, 0, stream>>>(
        (const float4*)EO, scores, mask, stmt, cov, out);
}